// Round 7
// baseline (334.978 us; speedup 1.0000x reference)
//
#include <hip/hip_runtime.h>
#include <cstdint>
#include <cstddef>

#define HID 128
#define LDK 72    // LDS row stride (bf16) for staged 64-k tiles
#define LDM 136   // LDS row stride (bf16) for full-128-k mean tile
#define EPB 4096  // edges per block in bucket pass
#define CAP 8192  // per-bucket capacity in ebuf/csr16 (mean load 4096, sigma 64)

typedef __attribute__((ext_vector_type(8))) short short8;
typedef __attribute__((ext_vector_type(4))) float floatx4;

__device__ __forceinline__ unsigned short f2bf(float f) {
  union { float f; uint32_t u; } c; c.f = f;
  uint32_t u = c.u;
  uint32_t r = (u + 0x7FFFu + ((u >> 16) & 1u)) >> 16;   // RNE
  return (unsigned short)r;
}
__device__ __forceinline__ float bflo(uint32_t v) { return __uint_as_float(v << 16); }
__device__ __forceinline__ float bfhi(uint32_t v) { return __uint_as_float(v & 0xFFFF0000u); }
__device__ __forceinline__ float bf2f(unsigned short s) { return __uint_as_float(((uint32_t)s) << 16); }

// ---------------- bucket pass: group edges by dst>>8 into per-bucket CAP regions ----------------
// packed (src | dst_low<<16); requires N < 65536 (N=50000 ok). bcur[b] counts per bucket.

__global__ __launch_bounds__(256) void k_bucket(const int* __restrict__ src,
                                                const int* __restrict__ dst,
                                                int* __restrict__ bcur,
                                                uint32_t* __restrict__ ebuf,
                                                int E, int NB) {
  __shared__ int hist[256];
  __shared__ int lcur[256];
  const int t = threadIdx.x;
  const int base = blockIdx.x * EPB;
  hist[t] = 0;
  __syncthreads();

  uint32_t val[EPB / 256];
  int bk[EPB / 256];
  #pragma unroll
  for (int i = 0; i < EPB / 256; ++i) {
    int e = base + i * 256 + t;
    bk[i] = -1;
    if (e < E) {
      int d = dst[e];
      int s = src[e];
      bk[i] = d >> 8;
      val[i] = (uint32_t)s | ((uint32_t)(d & 255) << 16);
      atomicAdd(&hist[bk[i]], 1);
    }
  }
  __syncthreads();
  if (t < NB) {
    int c = hist[t];
    lcur[t] = c ? atomicAdd(&bcur[t], c) : 0;
  }
  __syncthreads();
  #pragma unroll
  for (int i = 0; i < EPB / 256; ++i) {
    if (bk[i] >= 0) {
      int pos = bk[i] * CAP + atomicAdd(&lcur[bk[i]], 1);
      ebuf[pos] = val[i];
    }
  }
}

// fill pass: one block per bucket. Builds rowbeg/rowend for its 256 nodes
// (LDS histogram + scan) and packs csr16 within the bucket's CAP region.
__global__ __launch_bounds__(256) void k_bucket_fill2(const uint32_t* __restrict__ ebuf,
                                                      const int* __restrict__ bcur,
                                                      int* __restrict__ rowbeg,
                                                      int* __restrict__ rowend,
                                                      unsigned short* __restrict__ csr16,
                                                      int N) {
  __shared__ int hist[256];
  __shared__ int scan[256];
  const int b = blockIdx.x;
  const int t = threadIdx.x;
  hist[t] = 0;
  __syncthreads();
  const int lo = b * CAP;
  const int hi = lo + bcur[b];
  for (int i = lo + t; i < hi; i += 256) atomicAdd(&hist[ebuf[i] >> 16], 1);
  __syncthreads();
  int v = hist[t];
  scan[t] = v;
  __syncthreads();
  #pragma unroll
  for (int off = 1; off < 256; off <<= 1) {
    int add = (t >= off) ? scan[t - off] : 0;
    __syncthreads();
    scan[t] += add;
    __syncthreads();
  }
  int excl = scan[t] - v;
  int node = (b << 8) + t;
  if (node < N) {
    rowbeg[node] = lo + excl;
    rowend[node] = lo + excl + v;
  }
  hist[t] = lo + excl;   // reuse as cursor
  __syncthreads();
  for (int i = lo + t; i < hi; i += 256) {
    uint32_t e = ebuf[i];
    int pos = atomicAdd(&hist[e >> 16], 1);
    csr16[pos] = (unsigned short)(e & 0xFFFFu);
  }
}

// ---------------- fp32 -> bf16 cast ----------------

__global__ __launch_bounds__(256) void k_cast_bf16(const float* __restrict__ src,
                                                   unsigned short* __restrict__ dst, int n4) {
  int i = blockIdx.x * 256 + threadIdx.x;
  if (i < n4) {
    float4 v = ((const float4*)src)[i];
    uint32_t lo = (uint32_t)f2bf(v.x) | ((uint32_t)f2bf(v.y) << 16);
    uint32_t hi = (uint32_t)f2bf(v.z) | ((uint32_t)f2bf(v.w) << 16);
    ((uint2*)dst)[i] = make_uint2(lo, hi);
  }
}

// ---------------- fused SAGE layer: gather-mean into LDS, then MFMA GEMM ----------------
// out = relu(mean@WL^T + feat@WR^T + b). Block = 128 rows, 4 waves.
// Phase 1: wave-per-node gather (8 rows in flight, register accumulate, zero atomics)
//          -> means (bf16) into sMean[128][LDM].
// Phase 2: 4 K-stages; A-operand from sMean (stages 0,1) or staged feat (2,3).
// If pooled != null: segment-reduce the output tile by sorted batch id instead of storing.

__global__ __launch_bounds__(256, 2) void k_sage_layer(const unsigned short* __restrict__ feat,
                                                       const int* __restrict__ rowbeg,
                                                       const int* __restrict__ rowend,
                                                       const unsigned short* __restrict__ csr16,
                                                       const float* __restrict__ WL,
                                                       const float* __restrict__ WR,
                                                       const float* __restrict__ bias,
                                                       unsigned short* __restrict__ outb,
                                                       const int* __restrict__ batch,
                                                       float* __restrict__ pooled,
                                                       int M, int relu) {
  __shared__ __align__(16) unsigned short sMean[128 * LDM];  // 34816 B; reused as sH in pool path
  __shared__ __align__(16) unsigned short sA2[128 * LDK];    // 18432 B
  __shared__ __align__(16) unsigned short sW[128 * LDK];     // 18432 B
  __shared__ int sB[128];
  const int t = threadIdx.x;
  const int lane = t & 63;
  const int wave = t >> 6;
  const int row0 = blockIdx.x * 128;

  // ---- phase 1: gather means for this block's 128 nodes ----
  {
    const int grp = lane >> 4;
    const int fl  = lane & 15;
    for (int nn = wave; nn < 128; nn += 4) {
      int node = row0 + nn;
      int start = 0, end = 0;
      if (node < M) { start = rowbeg[node]; end = rowend[node]; }
      float a[8];
      #pragma unroll
      for (int i = 0; i < 8; ++i) a[i] = 0.f;
      for (int base = start; base < end; base += 64) {
        int m = end - base;
        if (m > 64) m = 64;
        int sidx = (base + lane < end) ? (int)csr16[base + lane] : 0;
        for (int j = 0; j < m; j += 8) {
          int j0 = j + grp, j1 = j + grp + 4;
          int s0 = __shfl(sidx, j0, 64);
          int s1 = __shfl(sidx, j1, 64);
          uint4 v0, v1;
          bool g0 = j0 < m, g1 = j1 < m;
          if (g0) v0 = *(const uint4*)(feat + (size_t)s0 * HID + fl * 8);
          if (g1) v1 = *(const uint4*)(feat + (size_t)s1 * HID + fl * 8);
          if (g0) {
            a[0] += bflo(v0.x); a[1] += bfhi(v0.x);
            a[2] += bflo(v0.y); a[3] += bfhi(v0.y);
            a[4] += bflo(v0.z); a[5] += bfhi(v0.z);
            a[6] += bflo(v0.w); a[7] += bfhi(v0.w);
          }
          if (g1) {
            a[0] += bflo(v1.x); a[1] += bfhi(v1.x);
            a[2] += bflo(v1.y); a[3] += bfhi(v1.y);
            a[4] += bflo(v1.z); a[5] += bfhi(v1.z);
            a[6] += bflo(v1.w); a[7] += bfhi(v1.w);
          }
        }
      }
      #pragma unroll
      for (int i = 0; i < 8; ++i) {
        a[i] += __shfl_xor(a[i], 16, 64);
        a[i] += __shfl_xor(a[i], 32, 64);
      }
      if (grp == 0) {
        int deg = end - start;
        float inv = 1.0f / (float)(deg > 1 ? deg : 1);
        uint4 o;
        o.x = (uint32_t)f2bf(a[0] * inv) | ((uint32_t)f2bf(a[1] * inv) << 16);
        o.y = (uint32_t)f2bf(a[2] * inv) | ((uint32_t)f2bf(a[3] * inv) << 16);
        o.z = (uint32_t)f2bf(a[4] * inv) | ((uint32_t)f2bf(a[5] * inv) << 16);
        o.w = (uint32_t)f2bf(a[6] * inv) | ((uint32_t)f2bf(a[7] * inv) << 16);
        *(uint4*)&sMean[nn * LDM + fl * 8] = o;
      }
    }
  }
  __syncthreads();

  // ---- phase 2: MFMA ----
  const int mhalf = (wave & 1) * 64;
  const int nhalf = (wave >> 1) * 64;
  const int ml = lane & 15;
  const int q  = lane >> 4;

  floatx4 acc[4][4];
  #pragma unroll
  for (int a = 0; a < 4; ++a)
    #pragma unroll
    for (int b = 0; b < 4; ++b) acc[a][b] = (floatx4){0.f, 0.f, 0.f, 0.f};

  for (int stage = 0; stage < 4; ++stage) {
    const float* __restrict__ Wsrc = (stage < 2) ? WL : WR;
    const int k0g = (stage & 1) * 64;
    if (stage) __syncthreads();

    // stage W: 128 rows x 64 fp32 -> bf16
    #pragma unroll
    for (int i = 0; i < 8; ++i) {
      int e = t + i * 256;
      int o = e >> 4, kc = (e & 15) * 4;
      float4 v = *(const float4*)(Wsrc + (size_t)o * HID + k0g + kc);
      uint32_t lo = (uint32_t)f2bf(v.x) | ((uint32_t)f2bf(v.y) << 16);
      uint32_t hi = (uint32_t)f2bf(v.z) | ((uint32_t)f2bf(v.w) << 16);
      *(uint2*)&sW[o * LDK + kc] = make_uint2(lo, hi);
    }
    // stage A2 (feat rows) only for stages 2,3
    if (stage >= 2) {
      #pragma unroll
      for (int i = 0; i < 4; ++i) {
        int seg = t + i * 256;
        int r = seg >> 3, kc = (seg & 7) * 8;
        int gr = row0 + r;
        float4 v = make_float4(0.f, 0.f, 0.f, 0.f);
        if (gr < M) v = *(const float4*)(feat + (size_t)gr * HID + k0g + kc);
        *(float4*)&sA2[r * LDK + kc] = v;
      }
    }
    __syncthreads();

    #pragma unroll
    for (int ks = 0; ks < 2; ++ks) {
      int kb = ks * 32 + q * 8;
      short8 af[4], bfr[4];
      if (stage < 2) {
        #pragma unroll
        for (int mt = 0; mt < 4; ++mt)
          af[mt] = *(const short8*)&sMean[(mhalf + mt * 16 + ml) * LDM + k0g + kb];
      } else {
        #pragma unroll
        for (int mt = 0; mt < 4; ++mt)
          af[mt] = *(const short8*)&sA2[(mhalf + mt * 16 + ml) * LDK + kb];
      }
      #pragma unroll
      for (int nt = 0; nt < 4; ++nt)
        bfr[nt] = *(const short8*)&sW[(nhalf + nt * 16 + ml) * LDK + kb];
      #pragma unroll
      for (int mt = 0; mt < 4; ++mt)
        #pragma unroll
        for (int nt = 0; nt < 4; ++nt)
          acc[mt][nt] = __builtin_amdgcn_mfma_f32_16x16x32_bf16(af[mt], bfr[nt], acc[mt][nt], 0, 0, 0);
    }
  }

  if (pooled == nullptr) {
    // C/D layout: col=lane&15, row=q*4+reg
    #pragma unroll
    for (int nt = 0; nt < 4; ++nt) {
      int gcol = nhalf + nt * 16 + ml;
      float bv = bias[gcol];
      #pragma unroll
      for (int mt = 0; mt < 4; ++mt) {
        #pragma unroll
        for (int r = 0; r < 4; ++r) {
          int grow = row0 + mhalf + mt * 16 + q * 4 + r;
          if (grow < M) {
            float v = acc[mt][nt][r] + bv;
            if (relu) v = fmaxf(v, 0.f);
            outb[(size_t)grow * HID + gcol] = f2bf(v);
          }
        }
      }
    }
  } else {
    __syncthreads();
    unsigned short* sH = sMean;   // overlay: 128*128 <= 128*LDM
    #pragma unroll
    for (int nt = 0; nt < 4; ++nt) {
      int gcol = nhalf + nt * 16 + ml;
      float bv = bias[gcol];
      #pragma unroll
      for (int mt = 0; mt < 4; ++mt) {
        #pragma unroll
        for (int r = 0; r < 4; ++r) {
          int lr = mhalf + mt * 16 + q * 4 + r;
          float v = acc[mt][nt][r] + bv;
          if (relu) v = fmaxf(v, 0.f);
          sH[lr * 128 + gcol] = f2bf(v);
        }
      }
    }
    if (t < 128) sB[t] = (row0 + t < M) ? batch[row0 + t] : -1;
    __syncthreads();
    const int f = t & 127, half = t >> 7;
    float pacc = 0.f;
    int curg = -1;
    for (int n = half; n < 128; n += 2) {
      int g = sB[n];
      if (g != curg) {
        if (curg >= 0) atomicAdd(&pooled[(size_t)curg * HID + f], pacc);
        curg = g; pacc = 0.f;
      }
      if (g >= 0) pacc += bf2f(sH[n * 128 + f]);
    }
    if (curg >= 0) atomicAdd(&pooled[(size_t)curg * HID + f], pacc);
  }
}

// ---------------- classifier ----------------

__device__ __forceinline__ int lower_bound_dev(const int* a, int n, int key) {
  int lo = 0, hi = n;
  while (lo < hi) {
    int mid = (lo + hi) >> 1;
    if (a[mid] < key) lo = mid + 1; else hi = mid;
  }
  return lo;
}

__global__ __launch_bounds__(256) void k_classify(const float* __restrict__ pooled,
                                                  const int* __restrict__ batch,
                                                  const float* __restrict__ cw,
                                                  const float* __restrict__ cb,
                                                  float* __restrict__ out, int N) {
  __shared__ int bnds[2];
  __shared__ float sp[128];
  __shared__ float part[2][128];
  int g = blockIdx.x;
  int t = threadIdx.x;
  if (t == 0) bnds[0] = lower_bound_dev(batch, N, g);
  if (t == 1) bnds[1] = lower_bound_dev(batch, N, g + 1);
  __syncthreads();
  int cnt = bnds[1] - bnds[0];
  float inv = 1.0f / (float)(cnt > 1 ? cnt : 1);
  if (t < 128) sp[t] = pooled[(size_t)g * HID + t] * inv;
  __syncthreads();
  int o = t & 127, kh = t >> 7;
  float a = 0.f;
  #pragma unroll 4
  for (int k = kh * 64; k < kh * 64 + 64; ++k) a += sp[k] * cw[(size_t)o * HID + k];
  part[kh][o] = a;
  __syncthreads();
  if (t < 128) out[(size_t)g * HID + t] = part[0][t] + part[1][t] + cb[t];
}

// ---------------- launch ----------------

extern "C" void kernel_launch(void* const* d_in, const int* in_sizes, int n_in,
                              void* d_out, int out_size, void* d_ws, size_t ws_size,
                              hipStream_t stream) {
  const float* x     = (const float*)d_in[0];
  const int*   ei    = (const int*)d_in[1];
  const int*   batch = (const int*)d_in[2];
  const float* wl1   = (const float*)d_in[3];
  const float* b1    = (const float*)d_in[4];
  const float* wr1   = (const float*)d_in[5];
  const float* wl2   = (const float*)d_in[6];
  const float* b2    = (const float*)d_in[7];
  const float* wr2   = (const float*)d_in[8];
  const float* cw    = (const float*)d_in[9];
  const float* cb    = (const float*)d_in[10];
  float* out = (float*)d_out;

  const int N = in_sizes[0] / HID;   // 50000 (must be < 65536 for edge packing)
  const int E = in_sizes[1] / 2;     // 800000
  const int G = out_size / HID;      // 128
  const int* src = ei;
  const int* dst = ei + E;

  // workspace layout
  char* w = (char*)d_ws;
  int*      bcur   = (int*)(w);                    // 256 ints (zeroed)
  float*    pooled = (float*)(w + 1024);           // 16384 fp32 (zeroed) -> ends 66560
  int*      rowbeg = (int*)(w + 66560);            // N ints -> ends 266560
  int*      rowend = (int*)(w + 266560);           // N ints -> ends 466560
  uint32_t* ebuf   = (uint32_t*)(w + 466944);      // NB*CAP uints (6.42 MB) -> ends 6889472
  unsigned short* csr16 = (unsigned short*)(w + 6889472);   // NB*CAP ushort (3.2 MB) -> ends 10100736
  unsigned short* xb    = (unsigned short*)(w + 10100736);  // N*128 bf16
  unsigned short* h1b   = (unsigned short*)(w + 10100736 + 12800000);  // N*128 bf16

  const int NB = (N + 255) >> 8;     // 196 buckets
  const int sageBlocks = (N + 127) / 128;
  const int castBlocks = (N * HID / 4 + 255) / 256;
  const int bktBlocks  = (E + EPB - 1) / EPB;

  hipMemsetAsync(w, 0, 66560, stream);   // bcur + pooled

  hipLaunchKernelGGL(k_bucket,       dim3(bktBlocks), dim3(256), 0, stream, src, dst, bcur, ebuf, E, NB);
  hipLaunchKernelGGL(k_bucket_fill2, dim3(NB),  dim3(256), 0, stream, ebuf, bcur, rowbeg, rowend, csr16, N);
  hipLaunchKernelGGL(k_cast_bf16,    dim3(castBlocks), dim3(256), 0, stream, x, xb, N * HID / 4);

  // layer 1 (fused aggregate + GEMM)
  hipLaunchKernelGGL(k_sage_layer, dim3(sageBlocks), dim3(256), 0, stream,
                     xb, rowbeg, rowend, csr16, wl1, wr1, b1, h1b,
                     (const int*)nullptr, (float*)nullptr, N, 1);
  // layer 2 (fused aggregate + GEMM + mean-pool)
  hipLaunchKernelGGL(k_sage_layer, dim3(sageBlocks), dim3(256), 0, stream,
                     h1b, rowbeg, rowend, csr16, wl2, wr2, b2,
                     (unsigned short*)nullptr, batch, pooled, N, 1);
  // classifier
  hipLaunchKernelGGL(k_classify, dim3(G), dim3(256), 0, stream, pooled, batch, cw, cb, out, N);
}

// Round 8
// 232.653 us; speedup vs baseline: 1.4398x; 1.4398x over previous
//
#include <hip/hip_runtime.h>
#include <cstdint>
#include <cstddef>

#define HID 128
#define LDK 72    // GEMM LDS row stride in bf16 elems (64 + 8 pad)
#define EPB 4096  // edges per block in bucket pass
#define CAP 8192  // per-bucket capacity in ebuf/csr16 (mean load 4096, sigma ~64)

typedef __attribute__((ext_vector_type(8))) short short8;
typedef __attribute__((ext_vector_type(4))) float floatx4;

__device__ __forceinline__ unsigned short f2bf(float f) {
  union { float f; uint32_t u; } c; c.f = f;
  uint32_t u = c.u;
  uint32_t r = (u + 0x7FFFu + ((u >> 16) & 1u)) >> 16;   // RNE
  return (unsigned short)r;
}
__device__ __forceinline__ float bflo(uint32_t v) { return __uint_as_float(v << 16); }
__device__ __forceinline__ float bfhi(uint32_t v) { return __uint_as_float(v & 0xFFFF0000u); }
__device__ __forceinline__ float bf2f(unsigned short s) { return __uint_as_float(((uint32_t)s) << 16); }

// ---------------- bucket pass: group edges by dst>>8 into per-bucket CAP regions ----------------
// packed (src | dst_low<<16); requires N < 65536 (N=50000 ok). bcur[b] = per-bucket count.

__global__ __launch_bounds__(256) void k_bucket(const int* __restrict__ src,
                                                const int* __restrict__ dst,
                                                int* __restrict__ bcur,
                                                uint32_t* __restrict__ ebuf,
                                                int E, int NB) {
  __shared__ int hist[256];
  __shared__ int lcur[256];
  const int t = threadIdx.x;
  const int base = blockIdx.x * EPB;
  hist[t] = 0;
  __syncthreads();

  uint32_t val[EPB / 256];
  int bk[EPB / 256];
  #pragma unroll
  for (int i = 0; i < EPB / 256; ++i) {
    int e = base + i * 256 + t;
    bk[i] = -1;
    if (e < E) {
      int d = dst[e];
      int s = src[e];
      bk[i] = d >> 8;
      val[i] = (uint32_t)s | ((uint32_t)(d & 255) << 16);
      atomicAdd(&hist[bk[i]], 1);
    }
  }
  __syncthreads();
  if (t < NB) {
    int c = hist[t];
    lcur[t] = c ? atomicAdd(&bcur[t], c) : 0;
  }
  __syncthreads();
  #pragma unroll
  for (int i = 0; i < EPB / 256; ++i) {
    if (bk[i] >= 0) {
      int pos = bk[i] * CAP + atomicAdd(&lcur[bk[i]], 1);
      ebuf[pos] = val[i];
    }
  }
}

// fill pass: one block per bucket. Builds rowbeg/rowend for its 256 nodes
// (LDS histogram + scan) and packs csr16 within the bucket's CAP region.
__global__ __launch_bounds__(256) void k_bucket_fill2(const uint32_t* __restrict__ ebuf,
                                                      const int* __restrict__ bcur,
                                                      int* __restrict__ rowbeg,
                                                      int* __restrict__ rowend,
                                                      unsigned short* __restrict__ csr16,
                                                      int N) {
  __shared__ int hist[256];
  __shared__ int scan[256];
  const int b = blockIdx.x;
  const int t = threadIdx.x;
  hist[t] = 0;
  __syncthreads();
  const int lo = b * CAP;
  const int hi = lo + bcur[b];
  for (int i = lo + t; i < hi; i += 256) atomicAdd(&hist[ebuf[i] >> 16], 1);
  __syncthreads();
  int v = hist[t];
  scan[t] = v;
  __syncthreads();
  #pragma unroll
  for (int off = 1; off < 256; off <<= 1) {
    int add = (t >= off) ? scan[t - off] : 0;
    __syncthreads();
    scan[t] += add;
    __syncthreads();
  }
  int excl = scan[t] - v;
  int node = (b << 8) + t;
  if (node < N) {
    rowbeg[node] = lo + excl;
    rowend[node] = lo + excl + v;
  }
  hist[t] = lo + excl;   // reuse as cursor
  __syncthreads();
  for (int i = lo + t; i < hi; i += 256) {
    uint32_t e = ebuf[i];
    int pos = atomicAdd(&hist[e >> 16], 1);
    csr16[pos] = (unsigned short)(e & 0xFFFFu);
  }
}

// ---------------- fp32 -> bf16 cast ----------------

__global__ __launch_bounds__(256) void k_cast_bf16(const float* __restrict__ src,
                                                   unsigned short* __restrict__ dst, int n4) {
  int i = blockIdx.x * 256 + threadIdx.x;
  if (i < n4) {
    float4 v = ((const float4*)src)[i];
    uint32_t lo = (uint32_t)f2bf(v.x) | ((uint32_t)f2bf(v.y) << 16);
    uint32_t hi = (uint32_t)f2bf(v.z) | ((uint32_t)f2bf(v.w) << 16);
    ((uint2*)dst)[i] = make_uint2(lo, hi);
  }
}

// ---------------- mean aggregation: one wave per node, 16 rows in flight ----------------
// lane = grp*16 + fl; grp in 0..3. Per inner iter each lane issues FOUR
// independent uint4 gathers (rows j+grp, +4, +8, +12). Mean degree 16 -> a
// typical node issues all its row-loads before any dependent add retires.
// Registers accumulate; zero atomics anywhere.

__global__ __launch_bounds__(256) void k_aggregate(const unsigned short* __restrict__ feat,
                                                   const int* __restrict__ rowbeg,
                                                   const int* __restrict__ rowend,
                                                   const unsigned short* __restrict__ csr16,
                                                   unsigned short* __restrict__ outmean, int N) {
  int wid = blockIdx.x * 4 + (threadIdx.x >> 6);
  int lane = threadIdx.x & 63;
  if (wid >= N) return;
  int start = rowbeg[wid];
  int end   = rowend[wid];
  const int grp = lane >> 4;
  const int fl  = lane & 15;
  float a[8];
  #pragma unroll
  for (int i = 0; i < 8; ++i) a[i] = 0.f;

  for (int base = start; base < end; base += 64) {
    int m = end - base;
    if (m > 64) m = 64;
    int sidx = (base + lane < end) ? (int)csr16[base + lane] : 0;
    for (int j = 0; j < m; j += 16) {
      int j0 = j + grp, j1 = j + grp + 4, j2 = j + grp + 8, j3 = j + grp + 12;
      int s0 = __shfl(sidx, j0, 64);
      int s1 = __shfl(sidx, j1, 64);
      int s2 = __shfl(sidx, j2, 64);
      int s3 = __shfl(sidx, j3, 64);
      bool g0 = j0 < m, g1 = j1 < m, g2 = j2 < m, g3 = j3 < m;
      uint4 v0, v1, v2, v3;
      if (g0) v0 = *(const uint4*)(feat + (size_t)s0 * HID + fl * 8);
      if (g1) v1 = *(const uint4*)(feat + (size_t)s1 * HID + fl * 8);
      if (g2) v2 = *(const uint4*)(feat + (size_t)s2 * HID + fl * 8);
      if (g3) v3 = *(const uint4*)(feat + (size_t)s3 * HID + fl * 8);
      if (g0) {
        a[0] += bflo(v0.x); a[1] += bfhi(v0.x);
        a[2] += bflo(v0.y); a[3] += bfhi(v0.y);
        a[4] += bflo(v0.z); a[5] += bfhi(v0.z);
        a[6] += bflo(v0.w); a[7] += bfhi(v0.w);
      }
      if (g1) {
        a[0] += bflo(v1.x); a[1] += bfhi(v1.x);
        a[2] += bflo(v1.y); a[3] += bfhi(v1.y);
        a[4] += bflo(v1.z); a[5] += bfhi(v1.z);
        a[6] += bflo(v1.w); a[7] += bfhi(v1.w);
      }
      if (g2) {
        a[0] += bflo(v2.x); a[1] += bfhi(v2.x);
        a[2] += bflo(v2.y); a[3] += bfhi(v2.y);
        a[4] += bflo(v2.z); a[5] += bfhi(v2.z);
        a[6] += bflo(v2.w); a[7] += bfhi(v2.w);
      }
      if (g3) {
        a[0] += bflo(v3.x); a[1] += bfhi(v3.x);
        a[2] += bflo(v3.y); a[3] += bfhi(v3.y);
        a[4] += bflo(v3.z); a[5] += bfhi(v3.z);
        a[6] += bflo(v3.w); a[7] += bfhi(v3.w);
      }
    }
  }
  #pragma unroll
  for (int i = 0; i < 8; ++i) {
    a[i] += __shfl_xor(a[i], 16, 64);
    a[i] += __shfl_xor(a[i], 32, 64);
  }
  if (grp == 0) {
    int deg = end - start;
    float inv = 1.0f / (float)(deg > 1 ? deg : 1);
    uint4 o;
    o.x = (uint32_t)f2bf(a[0] * inv) | ((uint32_t)f2bf(a[1] * inv) << 16);
    o.y = (uint32_t)f2bf(a[2] * inv) | ((uint32_t)f2bf(a[3] * inv) << 16);
    o.z = (uint32_t)f2bf(a[4] * inv) | ((uint32_t)f2bf(a[5] * inv) << 16);
    o.w = (uint32_t)f2bf(a[6] * inv) | ((uint32_t)f2bf(a[7] * inv) << 16);
    *(uint4*)(outmean + (size_t)wid * HID + fl * 8) = o;
  }
}

// ---------------- MFMA GEMM: relu(A1@WL^T + A2@WR^T + b) ----------------
// 128x128 block tile, 4 waves. If pooled != null, segment-reduce the output
// tile by (sorted) batch id into pooled[G][128] instead of storing rows.

__global__ __launch_bounds__(256, 2) void k_gemm_mfma(const unsigned short* __restrict__ A1,
                                                      const unsigned short* __restrict__ A2,
                                                      const float* __restrict__ WL,
                                                      const float* __restrict__ WR,
                                                      const float* __restrict__ bias,
                                                      unsigned short* __restrict__ outb,
                                                      const int* __restrict__ batch,
                                                      float* __restrict__ pooled,
                                                      int M, int relu) {
  __shared__ __align__(16) unsigned short sAB[2 * 128 * LDK];  // sA | sW; reused as sH
  __shared__ int sB[128];
  unsigned short* sA = sAB;
  unsigned short* sW = sAB + 128 * LDK;
  const int t = threadIdx.x;
  const int lane = t & 63;
  const int wave = t >> 6;
  const int row0 = blockIdx.x * 128;
  const int mhalf = (wave & 1) * 64;
  const int nhalf = (wave >> 1) * 64;
  const int ml = lane & 15;
  const int q  = lane >> 4;

  floatx4 acc[4][4];
  #pragma unroll
  for (int a = 0; a < 4; ++a)
    #pragma unroll
    for (int b = 0; b < 4; ++b) acc[a][b] = (floatx4){0.f, 0.f, 0.f, 0.f};

  for (int stage = 0; stage < 4; ++stage) {
    const unsigned short* __restrict__ Asrc = (stage < 2) ? A1 : A2;
    const float* __restrict__ Wsrc = (stage < 2) ? WL : WR;
    const int k0g = (stage & 1) * 64;
    if (stage) __syncthreads();

    #pragma unroll
    for (int i = 0; i < 4; ++i) {
      int seg = t + i * 256;
      int r = seg >> 3, kc = (seg & 7) * 8;
      int gr = row0 + r;
      float4 v = make_float4(0.f, 0.f, 0.f, 0.f);
      if (gr < M) v = *(const float4*)(Asrc + (size_t)gr * HID + k0g + kc);
      *(float4*)&sA[r * LDK + kc] = v;
    }
    #pragma unroll
    for (int i = 0; i < 8; ++i) {
      int e = t + i * 256;
      int o = e >> 4, kc = (e & 15) * 4;
      float4 v = *(const float4*)(Wsrc + (size_t)o * HID + k0g + kc);
      uint32_t lo = (uint32_t)f2bf(v.x) | ((uint32_t)f2bf(v.y) << 16);
      uint32_t hi = (uint32_t)f2bf(v.z) | ((uint32_t)f2bf(v.w) << 16);
      *(uint2*)&sW[o * LDK + kc] = make_uint2(lo, hi);
    }
    __syncthreads();

    #pragma unroll
    for (int ks = 0; ks < 2; ++ks) {
      int kb = ks * 32 + q * 8;
      short8 af[4], bfr[4];
      #pragma unroll
      for (int mt = 0; mt < 4; ++mt)
        af[mt] = *(const short8*)&sA[(mhalf + mt * 16 + ml) * LDK + kb];
      #pragma unroll
      for (int nt = 0; nt < 4; ++nt)
        bfr[nt] = *(const short8*)&sW[(nhalf + nt * 16 + ml) * LDK + kb];
      #pragma unroll
      for (int mt = 0; mt < 4; ++mt)
        #pragma unroll
        for (int nt = 0; nt < 4; ++nt)
          acc[mt][nt] = __builtin_amdgcn_mfma_f32_16x16x32_bf16(af[mt], bfr[nt], acc[mt][nt], 0, 0, 0);
    }
  }

  if (pooled == nullptr) {
    // C/D layout: col=lane&15, row=q*4+reg
    #pragma unroll
    for (int nt = 0; nt < 4; ++nt) {
      int gcol = nhalf + nt * 16 + ml;
      float bv = bias[gcol];
      #pragma unroll
      for (int mt = 0; mt < 4; ++mt) {
        #pragma unroll
        for (int r = 0; r < 4; ++r) {
          int grow = row0 + mhalf + mt * 16 + q * 4 + r;
          if (grow < M) {
            float v = acc[mt][nt][r] + bv;
            if (relu) v = fmaxf(v, 0.f);
            outb[(size_t)grow * HID + gcol] = f2bf(v);
          }
        }
      }
    }
  } else {
    __syncthreads();
    unsigned short* sH = sAB;
    #pragma unroll
    for (int nt = 0; nt < 4; ++nt) {
      int gcol = nhalf + nt * 16 + ml;
      float bv = bias[gcol];
      #pragma unroll
      for (int mt = 0; mt < 4; ++mt) {
        #pragma unroll
        for (int r = 0; r < 4; ++r) {
          int lr = mhalf + mt * 16 + q * 4 + r;
          float v = acc[mt][nt][r] + bv;
          if (relu) v = fmaxf(v, 0.f);
          sH[lr * 128 + gcol] = f2bf(v);
        }
      }
    }
    if (t < 128) sB[t] = (row0 + t < M) ? batch[row0 + t] : -1;
    __syncthreads();
    const int f = t & 127, half = t >> 7;
    float pacc = 0.f;
    int curg = -1;
    for (int n = half; n < 128; n += 2) {
      int g = sB[n];
      if (g != curg) {
        if (curg >= 0) atomicAdd(&pooled[(size_t)curg * HID + f], pacc);
        curg = g; pacc = 0.f;
      }
      if (g >= 0) pacc += bf2f(sH[n * 128 + f]);
    }
    if (curg >= 0) atomicAdd(&pooled[(size_t)curg * HID + f], pacc);
  }
}

// ---------------- classifier ----------------

__device__ __forceinline__ int lower_bound_dev(const int* a, int n, int key) {
  int lo = 0, hi = n;
  while (lo < hi) {
    int mid = (lo + hi) >> 1;
    if (a[mid] < key) lo = mid + 1; else hi = mid;
  }
  return lo;
}

__global__ __launch_bounds__(256) void k_classify(const float* __restrict__ pooled,
                                                  const int* __restrict__ batch,
                                                  const float* __restrict__ cw,
                                                  const float* __restrict__ cb,
                                                  float* __restrict__ out, int N) {
  __shared__ int bnds[2];
  __shared__ float sp[128];
  __shared__ float part[2][128];
  int g = blockIdx.x;
  int t = threadIdx.x;
  if (t == 0) bnds[0] = lower_bound_dev(batch, N, g);
  if (t == 1) bnds[1] = lower_bound_dev(batch, N, g + 1);
  __syncthreads();
  int cnt = bnds[1] - bnds[0];
  float inv = 1.0f / (float)(cnt > 1 ? cnt : 1);
  if (t < 128) sp[t] = pooled[(size_t)g * HID + t] * inv;
  __syncthreads();
  int o = t & 127, kh = t >> 7;
  float a = 0.f;
  #pragma unroll 4
  for (int k = kh * 64; k < kh * 64 + 64; ++k) a += sp[k] * cw[(size_t)o * HID + k];
  part[kh][o] = a;
  __syncthreads();
  if (t < 128) out[(size_t)g * HID + t] = part[0][t] + part[1][t] + cb[t];
}

// ---------------- launch ----------------

extern "C" void kernel_launch(void* const* d_in, const int* in_sizes, int n_in,
                              void* d_out, int out_size, void* d_ws, size_t ws_size,
                              hipStream_t stream) {
  const float* x     = (const float*)d_in[0];
  const int*   ei    = (const int*)d_in[1];
  const int*   batch = (const int*)d_in[2];
  const float* wl1   = (const float*)d_in[3];
  const float* b1    = (const float*)d_in[4];
  const float* wr1   = (const float*)d_in[5];
  const float* wl2   = (const float*)d_in[6];
  const float* b2    = (const float*)d_in[7];
  const float* wr2   = (const float*)d_in[8];
  const float* cw    = (const float*)d_in[9];
  const float* cb    = (const float*)d_in[10];
  float* out = (float*)d_out;

  const int N = in_sizes[0] / HID;   // 50000 (must be < 65536 for edge packing)
  const int E = in_sizes[1] / 2;     // 800000
  const int G = out_size / HID;      // 128
  const int* src = ei;
  const int* dst = ei + E;

  // workspace layout
  char* w = (char*)d_ws;
  int*      bcur   = (int*)(w);                    // 256 ints (zeroed)
  float*    pooled = (float*)(w + 1024);           // 16384 fp32 (zeroed) -> ends 66560
  int*      rowbeg = (int*)(w + 66560);            // N ints -> ends 266560
  int*      rowend = (int*)(w + 266560);           // N ints -> ends 466560
  uint32_t* ebuf   = (uint32_t*)(w + 466944);      // NB*CAP uints (6.42 MB)
  unsigned short* csr16 = (unsigned short*)(w + 6889472);   // NB*CAP ushort (3.2 MB)
  unsigned short* xb    = (unsigned short*)(w + 10100736);  // N*128 bf16
  unsigned short* meanb = (unsigned short*)(w + 10100736 + 12800000);  // N*128 bf16
  unsigned short* h1b   = (unsigned short*)(w + 10100736 + 25600000);  // N*128 bf16
  unsigned short* h2_dummy = xb;  // unused sentinel

  const int NB = (N + 255) >> 8;     // 196 buckets
  const int aggBlocks  = (N + 3) / 4;
  const int gemmBlocks = (N + 127) / 128;
  const int castBlocks = (N * HID / 4 + 255) / 256;
  const int bktBlocks  = (E + EPB - 1) / EPB;

  hipMemsetAsync(w, 0, 66560, stream);   // bcur + pooled

  hipLaunchKernelGGL(k_bucket,       dim3(bktBlocks), dim3(256), 0, stream, src, dst, bcur, ebuf, E, NB);
  hipLaunchKernelGGL(k_bucket_fill2, dim3(NB),  dim3(256), 0, stream, ebuf, bcur, rowbeg, rowend, csr16, N);
  hipLaunchKernelGGL(k_cast_bf16,    dim3(castBlocks), dim3(256), 0, stream, x, xb, N * HID / 4);

  // layer 1
  hipLaunchKernelGGL(k_aggregate, dim3(aggBlocks), dim3(256), 0, stream, xb, rowbeg, rowend, csr16, meanb, N);
  hipLaunchKernelGGL(k_gemm_mfma, dim3(gemmBlocks), dim3(256), 0, stream, meanb, xb, wl1, wr1, b1, h1b,
                     (const int*)nullptr, (float*)nullptr, N, 1);
  // layer 2 + fused pool
  hipLaunchKernelGGL(k_aggregate, dim3(aggBlocks), dim3(256), 0, stream, h1b, rowbeg, rowend, csr16, meanb, N);
  hipLaunchKernelGGL(k_gemm_mfma, dim3(gemmBlocks), dim3(256), 0, stream, meanb, h1b, wl2, wr2, b2,
                     h2_dummy, batch, pooled, N, 1);
  // classifier
  hipLaunchKernelGGL(k_classify, dim3(G), dim3(256), 0, stream, pooled, batch, cw, cb, out, N);
}